// Round 15
// baseline (2641.681 us; speedup 1.0000x reference)
//
#include <hip/hip_runtime.h>
#include <hip/hip_bf16.h>
#include <cstdint>

#define S_LEN 512
#define BATCH 64
#define IDIM  1024
#define HDIM  1024
#define G4    4096
#define NBLK  256   // recurrence grid: 4 batch-groups x 64 col-blocks

typedef __attribute__((ext_vector_type(8))) short short8;
typedef __attribute__((ext_vector_type(8))) unsigned short ushort8;
typedef __attribute__((ext_vector_type(4))) float f32x4;
typedef __attribute__((ext_vector_type(4))) unsigned short ushort4v;
typedef __attribute__((ext_vector_type(4))) unsigned int uint4v;

__device__ __forceinline__ unsigned short f2bf(float f){
  union { float f; unsigned u; } v; v.f = f;
  unsigned r = (v.u + 0x7fffu + ((v.u >> 16) & 1u)) >> 16;
  return (unsigned short)r;
}
__device__ __forceinline__ float bf2f(unsigned short s){
  union { unsigned u; float f; } v; v.u = ((unsigned)s) << 16;
  return v.f;
}
__device__ __forceinline__ float sigf(float x){ return 1.0f / (1.0f + __expf(-x)); }
__device__ __forceinline__ float tanhf_fast(float x){
  float e = __expf(2.0f * x);
  return 1.0f - 2.0f / (e + 1.0f);
}
__device__ __forceinline__ f32x4 mfma_bf16(short8 a, short8 b, f32x4 c){
  return __builtin_amdgcn_mfma_f32_16x16x32_bf16(a, b, c, 0, 0, 0);
}

// pack 8 f32 -> short8 bf16 via v_cvt_pk_bf16_f32 (RNE, == f2bf)
__device__ __forceinline__ short8 cvt8(f32x4 a, f32x4 b){
  union { unsigned u[4]; short8 s; } r;
  asm("v_cvt_pk_bf16_f32 %0, %1, %2" : "=v"(r.u[0]) : "v"(a[0]), "v"(a[1]));
  asm("v_cvt_pk_bf16_f32 %0, %1, %2" : "=v"(r.u[1]) : "v"(a[2]), "v"(a[3]));
  asm("v_cvt_pk_bf16_f32 %0, %1, %2" : "=v"(r.u[2]) : "v"(b[0]), "v"(b[1]));
  asm("v_cvt_pk_bf16_f32 %0, %1, %2" : "=v"(r.u[3]) : "v"(b[2]), "v"(b[3]));
  return r.s;
}

// ---- LLC-coherent (sc0 sc1) helpers; internal vmcnt(0) only (round-4 lesson).
__device__ __forceinline__ void load8_bypass(const unsigned short* p, short8* d){
  asm volatile(
    "global_load_dwordx4 %0, %8, off sc0 sc1\n\t"
    "global_load_dwordx4 %1, %8, off offset:64 sc0 sc1\n\t"
    "global_load_dwordx4 %2, %8, off offset:128 sc0 sc1\n\t"
    "global_load_dwordx4 %3, %8, off offset:192 sc0 sc1\n\t"
    "global_load_dwordx4 %4, %8, off offset:256 sc0 sc1\n\t"
    "global_load_dwordx4 %5, %8, off offset:320 sc0 sc1\n\t"
    "global_load_dwordx4 %6, %8, off offset:384 sc0 sc1\n\t"
    "global_load_dwordx4 %7, %8, off offset:448 sc0 sc1\n\t"
    "s_waitcnt vmcnt(0)"
    : "=&v"(d[0]), "=&v"(d[1]), "=&v"(d[2]), "=&v"(d[3]),
      "=&v"(d[4]), "=&v"(d[5]), "=&v"(d[6]), "=&v"(d[7])
    : "v"(p)
    : "memory");
}
// In(s+2) f32 prefetch: 16 dwordx4, NO internal waitcnt — pinned issue slot;
// retired by the pre-flag vmcnt(0) later in the same step (clean poll after).
__device__ __forceinline__ void load16f_nowait(const float* p, f32x4* d){
  asm volatile(
    "global_load_dwordx4 %0, %16, off\n\t"
    "global_load_dwordx4 %1, %16, off offset:16\n\t"
    "global_load_dwordx4 %2, %16, off offset:128\n\t"
    "global_load_dwordx4 %3, %16, off offset:144\n\t"
    "global_load_dwordx4 %4, %16, off offset:256\n\t"
    "global_load_dwordx4 %5, %16, off offset:272\n\t"
    "global_load_dwordx4 %6, %16, off offset:384\n\t"
    "global_load_dwordx4 %7, %16, off offset:400\n\t"
    "global_load_dwordx4 %8, %16, off offset:512\n\t"
    "global_load_dwordx4 %9, %16, off offset:528\n\t"
    "global_load_dwordx4 %10, %16, off offset:640\n\t"
    "global_load_dwordx4 %11, %16, off offset:656\n\t"
    "global_load_dwordx4 %12, %16, off offset:768\n\t"
    "global_load_dwordx4 %13, %16, off offset:784\n\t"
    "global_load_dwordx4 %14, %16, off offset:896\n\t"
    "global_load_dwordx4 %15, %16, off offset:912"
    : "=&v"(d[0]), "=&v"(d[1]), "=&v"(d[2]), "=&v"(d[3]),
      "=&v"(d[4]), "=&v"(d[5]), "=&v"(d[6]), "=&v"(d[7]),
      "=&v"(d[8]), "=&v"(d[9]), "=&v"(d[10]), "=&v"(d[11]),
      "=&v"(d[12]), "=&v"(d[13]), "=&v"(d[14]), "=&v"(d[15])
    : "v"(p)
    : "memory");
}
__device__ __forceinline__ void store_short_bypass(unsigned short* p, unsigned v){
  asm volatile("global_store_short %0, %1, off sc0 sc1" :: "v"(p), "v"(v) : "memory");
}
__device__ __forceinline__ void store_dword_bypass(unsigned* p, unsigned v){
  asm volatile("global_store_dword %0, %1, off sc0 sc1" :: "v"(p), "v"(v) : "memory");
}
__device__ __forceinline__ uint4v load4_flags_bypass(const unsigned* p){
  uint4v f;
  asm volatile("global_load_dwordx4 %0, %1, off sc0 sc1\n\ts_waitcnt vmcnt(0)"
               : "=&v"(f) : "v"(p) : "memory");
  return f;
}

// ---------------------------------------------------------------------------
// prep: pack BOTH W_hh and W_ih into per-(cb,wave,gate,ks) MFMA-B-fragment
// order (bf16) — identical mapping, two buffers. Also bias sum + h0 seed.
// ---------------------------------------------------------------------------
__global__ __launch_bounds__(256) void prep_kernel(
    const float* __restrict__ Whh, const float* __restrict__ Wih,
    const float* __restrict__ bih, const float* __restrict__ bhh,
    const float* __restrict__ h0, unsigned short* __restrict__ WpackHH,
    unsigned short* __restrict__ WpackIH, float* __restrict__ biasSum,
    unsigned short* __restrict__ hA){
  int i = blockIdx.x * 256 + threadIdx.x;
  if (i < G4) biasSum[i] = bih[i] + bhh[i];
  if (i < BATCH*HDIM) hA[i] = f2bf(h0[i]);
  int p = (i < G4*HDIM) ? i : i - G4*HDIM;
  int e = p & 7, l = (p >> 3) & 63, ks = (p >> 9) & 7;
  int gate = (p >> 12) & 3, w = (p >> 14) & 3, cb = p >> 16;
  int row = gate * HDIM + cb * 16 + (l & 15);
  int k = w * 256 + ks * 32 + (l >> 4) * 8 + e;
  if (i < G4*HDIM) WpackHH[p] = f2bf(Whh[row * HDIM + k]);
  else             WpackIH[p] = f2bf(Wih[row * IDIM + k]);
}

// ---------------------------------------------------------------------------
// FUSED recurrence, round-15: In conversion fused (no convert kernel, no InB
// buffer). In(s+2) prefetched as f32 via pinned no-wait asm (r14 slot: after
// h-load, drained by pre-flag vmcnt(0)); converted to bf16 fragments at step
// top via v_cvt_pk_bf16_f32 (~30 ns). Single fpre/inr buffers (in-order WAR
// safe). r13 vectorized LDS partials + r7 sync skeleton.
// ---------------------------------------------------------------------------
__global__ __launch_bounds__(256, 1) void recur_kernel(
    const float* __restrict__ h0, const float* __restrict__ c0,
    const float* __restrict__ ret, const unsigned short* __restrict__ WpackHH,
    const unsigned short* __restrict__ WpackIH, const float* __restrict__ In,
    const float* __restrict__ biasSum, unsigned short* __restrict__ hA,
    unsigned short* __restrict__ hB, float* __restrict__ out,
    float* __restrict__ hc_out, unsigned* __restrict__ flags){
  __shared__ __align__(16) float partA[5120];   // [(m*16+n)*20 + w*4 + gate]
  __shared__ __align__(16) float partB[5120];

  const int bid = blockIdx.x;
  const int cb = bid & 63, g = bid >> 6;
  const int tid = threadIdx.x;
  const int w = tid >> 6, l = tid & 63;
  const int lm = l & 15, lq = l >> 4;

  // W fragments for this (cb, wave): hh + ih, 4 gates x 8 ks each
  short8 WfH[4][8], WfI[4][8];
  {
    const short8* wph = reinterpret_cast<const short8*>(WpackHH)
                      + (size_t)(cb * 4 + w) * 2048 + l;
    const short8* wpi = reinterpret_cast<const short8*>(WpackIH)
                      + (size_t)(cb * 4 + w) * 2048 + l;
    #pragma unroll
    for (int gate = 0; gate < 4; ++gate)
      #pragma unroll
      for (int ks = 0; ks < 8; ++ks){
        WfH[gate][ks] = wph[(gate * 8 + ks) * 64];
        WfI[gate][ks] = wpi[(gate * 8 + ks) * 64];
      }
  }

  const int bl = tid >> 4, j = tid & 15;   // batch-in-group, col-in-block
  const int bglob = g * 16 + bl, jglob = cb * 16 + j;
  float c_reg = c0[bglob * HDIM + jglob];
  float h_reg = h0[bglob * HDIM + jglob];
  float r_reg = ret[jglob];
  float bias_reg[4];
  #pragma unroll
  for (int gate = 0; gate < 4; ++gate)
    bias_reg[gate] = biasSum[gate * 1024 + jglob];

  // per-lane In source offset (element units; same fragment geometry as h)
  const size_t in_off = (size_t)(g * 16 + lm) * 1024 + w * 256 + lq * 8;

  unsigned* gflags = flags + g * 1024;   // one 64B line per block: [cb*16 + w]

  // ---- prologue: compute xv(0) from In(0) (f32 direct) ----
  float xv[4];
  {
    const f32x4* fp0 = reinterpret_cast<const f32x4*>(In + in_off);
    f32x4 accI[4];
    #pragma unroll
    for (int gate = 0; gate < 4; ++gate) accI[gate] = (f32x4){0.f,0.f,0.f,0.f};
    #pragma unroll
    for (int ks = 0; ks < 8; ++ks){
      short8 in8 = cvt8(fp0[ks * 8], fp0[ks * 8 + 1]);
      #pragma unroll
      for (int gate = 0; gate < 4; ++gate)
        accI[gate] = mfma_bf16(in8, WfI[gate][ks], accI[gate]);
    }
    #pragma unroll
    for (int r = 0; r < 4; ++r){
      f32x4 vB = (f32x4){accI[0][r], accI[1][r], accI[2][r], accI[3][r]};
      *reinterpret_cast<f32x4*>(&partB[((lq * 4 + r) * 16 + lm) * 20 + w * 4]) = vB;
    }
    __syncthreads();
    f32x4 s0 = (f32x4){bias_reg[0], bias_reg[1], bias_reg[2], bias_reg[3]};
    #pragma unroll
    for (int ww = 0; ww < 4; ++ww)
      s0 += *reinterpret_cast<const f32x4*>(&partB[tid * 20 + ww * 4]);
    xv[0] = s0[0]; xv[1] = s0[1]; xv[2] = s0[2]; xv[3] = s0[3];
    __syncthreads();   // protect partB before loop reuse
  }

  // preload In(1) f32 into fpre (plain loads; compiler inserts waits)
  f32x4 fpre[16];
  {
    const f32x4* fp1 = reinterpret_cast<const f32x4*>(In + 65536 + in_off);
    #pragma unroll
    for (int ks = 0; ks < 8; ++ks){
      fpre[2 * ks]     = fp1[ks * 8];
      fpre[2 * ks + 1] = fp1[ks * 8 + 1];
    }
  }

  for (int s = 0; s < S_LEN; ++s){
    const unsigned short* cur = (s & 1) ? hB : hA;
    unsigned short* nxt = (s & 1) ? hA : hB;

    // convert In(s+1) fragments (fpre valid: drained by last step's vmcnt(0))
    short8 inr[8];
    #pragma unroll
    for (int ks = 0; ks < 8; ++ks)
      inr[ks] = cvt8(fpre[2 * ks], fpre[2 * ks + 1]);

    // h load (LLC-coherent, internal vmcnt(0))
    const unsigned short* hp = cur + (size_t)(g * 16 + lm) * HDIM + w * 256 + lq * 8;
    short8 hr[8];
    load8_bypass(hp, hr);

    // In(s+2) f32 prefetch: pinned slot, no wait; hidden under MFMA/reduce,
    // collected by the pre-flag vmcnt(0) below (poll stays clean).
    {
      const int sn = (s + 2 < S_LEN) ? s + 2 : S_LEN - 1;
      load16f_nowait(In + (size_t)sn * 65536 + in_off, fpre);
    }

    // MFMA hh (h(s) @ Whh) and ih (In(s+1) @ Wih -> xg(s+1))
    f32x4 accH[4], accI[4];
    #pragma unroll
    for (int gate = 0; gate < 4; ++gate){
      accH[gate] = (f32x4){0.f,0.f,0.f,0.f};
      accI[gate] = (f32x4){0.f,0.f,0.f,0.f};
    }
    #pragma unroll
    for (int ks = 0; ks < 8; ++ks){
      accH[0] = mfma_bf16(hr[ks], WfH[0][ks], accH[0]);
      accH[1] = mfma_bf16(hr[ks], WfH[1][ks], accH[1]);
      accH[2] = mfma_bf16(hr[ks], WfH[2][ks], accH[2]);
      accH[3] = mfma_bf16(hr[ks], WfH[3][ks], accH[3]);
      accI[0] = mfma_bf16(inr[ks], WfI[0][ks], accI[0]);
      accI[1] = mfma_bf16(inr[ks], WfI[1][ks], accI[1]);
      accI[2] = mfma_bf16(inr[ks], WfI[2][ks], accI[2]);
      accI[3] = mfma_bf16(inr[ks], WfI[3][ks], accI[3]);
    }

    // partials to LDS: in-register gate transpose -> one f32x4 per r per buffer
    #pragma unroll
    for (int r = 0; r < 4; ++r){
      int a = ((lq * 4 + r) * 16 + lm) * 20 + w * 4;
      f32x4 vA = (f32x4){accH[0][r], accH[1][r], accH[2][r], accH[3][r]};
      f32x4 vB = (f32x4){accI[0][r], accI[1][r], accI[2][r], accI[3][r]};
      *reinterpret_cast<f32x4*>(&partA[a]) = vA;
      *reinterpret_cast<f32x4*>(&partB[a]) = vB;
    }
    __syncthreads();   // sync#1

    // reduce hh + xv(s) -> gates; update; h' store
    f32x4 gs = (f32x4){xv[0], xv[1], xv[2], xv[3]};
    #pragma unroll
    for (int ww = 0; ww < 4; ++ww)
      gs += *reinterpret_cast<const f32x4*>(&partA[tid * 20 + ww * 4]);
    float ig = sigf(gs[0]), fg = sigf(gs[1]);
    float gt = tanhf_fast(gs[2]), og = sigf(gs[3]);
    float cy = fg * c_reg + ig * gt;
    float hy = og * tanhf_fast(cy);
    hy = r_reg * h_reg + (1.0f - r_reg) * hy;
    c_reg = cy; h_reg = hy;
    store_short_bypass(&nxt[bglob * HDIM + jglob], (unsigned)f2bf(hy));

    // ---- flag ASAP: drain h' (+ In prefetch, already landed), then arrival ----
    asm volatile("s_waitcnt vmcnt(0)" ::: "memory");
    const unsigned tgt = (unsigned)(s + 1);
    if (l == 0)
      store_dword_bypass(&gflags[cb * 16 + w], tgt);  // wave arrival

    // reduce ih partials -> xv(s+1)  (off the inter-block critical path)
    {
      f32x4 sB = (f32x4){bias_reg[0], bias_reg[1], bias_reg[2], bias_reg[3]};
      #pragma unroll
      for (int ww = 0; ww < 4; ++ww)
        sB += *reinterpret_cast<const f32x4*>(&partB[tid * 20 + ww * 4]);
      xv[0] = sB[0]; xv[1] = sB[1]; xv[2] = sB[2]; xv[3] = sB[3];
    }

    if (w == 0){                    // wave 0 polls with a CLEAN vmcnt
      const unsigned* fp = gflags + (l << 4);
      unsigned spins = 0;
      for (;;){
        uint4v f = load4_flags_bypass(fp);
        if (f[0] >= tgt && f[1] >= tgt && f[2] >= tgt && f[3] >= tgt) break;
        __builtin_amdgcn_s_sleep(1);
        if (++spins > 50000000u) break;   // safety bailout, never expected
      }
    }
    __syncthreads();   // sync#2: all waves see the barrier passed

    // out[] store AFTER the barrier: retires under next step's loads
    out[((size_t)s * BATCH + bglob) * HDIM + jglob] = h_reg;
  }

  hc_out[bglob * HDIM + jglob] = h_reg;
  hc_out[BATCH * HDIM + bglob * HDIM + jglob] = c_reg;
}

// ---------------------------------------------------------------------------
extern "C" void kernel_launch(void* const* d_in, const int* in_sizes, int n_in,
                              void* d_out, int out_size, void* d_ws, size_t ws_size,
                              hipStream_t stream){
  const float* In  = (const float*)d_in[0];
  const float* h0  = (const float*)d_in[1];
  const float* c0  = (const float*)d_in[2];
  const float* Wih = (const float*)d_in[3];
  const float* Whh = (const float*)d_in[4];
  const float* bih = (const float*)d_in[5];
  const float* bhh = (const float*)d_in[6];
  const float* ret = (const float*)d_in[7];
  float* out = (float*)d_out;

  char* ws = (char*)d_ws;
  const size_t off_flags = 0;                          // 16 KB (4 groups x 4 KB)
  const size_t off_bias  = 16384;                      // 16 KB
  const size_t off_hA    = 32768;                      // 128 KB
  const size_t off_hB    = off_hA + 131072;
  const size_t off_wph   = off_hB + 131072;            // 8 MB (Whh pack)
  const size_t off_wpi   = off_wph + 8388608;          // 8 MB (Wih pack)
  const size_t need      = off_wpi + 8388608;

  unsigned*       flags   = (unsigned*)(ws + off_flags);
  float*          biasSum = (float*)(ws + off_bias);
  unsigned short* hA      = (unsigned short*)(ws + off_hA);
  unsigned short* hB      = (unsigned short*)(ws + off_hB);
  unsigned short* WpackHH = (unsigned short*)(ws + off_wph);
  unsigned short* WpackIH = (unsigned short*)(ws + off_wpi);

  if (ws_size < need) return;  // cannot run; fail validation loudly

  (void)hipMemsetAsync(ws + off_flags, 0, 16384, stream);
  prep_kernel<<<32768, 256, 0, stream>>>(Whh, Wih, bih, bhh, h0,
                                         WpackHH, WpackIH, biasSum, hA);

  float* hc_out = out + (size_t)S_LEN * BATCH * HDIM;
  recur_kernel<<<NBLK, 256, 0, stream>>>(h0, c0, ret, WpackHH, WpackIH, In,
                                         biasSum, hA, hB, out, hc_out, flags);
}

// Round 16
// 2324.194 us; speedup vs baseline: 1.1366x; 1.1366x over previous
//
#include <hip/hip_runtime.h>
#include <hip/hip_bf16.h>
#include <cstdint>

#define S_LEN 512
#define BATCH 64
#define IDIM  1024
#define HDIM  1024
#define G4    4096
#define NBLK  256   // recurrence grid: 4 batch-groups x 64 col-blocks

typedef __attribute__((ext_vector_type(8))) short short8;
typedef __attribute__((ext_vector_type(8))) unsigned short ushort8;
typedef __attribute__((ext_vector_type(4))) float f32x4;
typedef __attribute__((ext_vector_type(4))) unsigned short ushort4v;
typedef __attribute__((ext_vector_type(4))) unsigned int uint4v;

__device__ __forceinline__ unsigned short f2bf(float f){
  union { float f; unsigned u; } v; v.f = f;
  unsigned r = (v.u + 0x7fffu + ((v.u >> 16) & 1u)) >> 16;
  return (unsigned short)r;
}
__device__ __forceinline__ float bf2f(unsigned short s){
  union { unsigned u; float f; } v; v.u = ((unsigned)s) << 16;
  return v.f;
}
__device__ __forceinline__ float sigf(float x){ return 1.0f / (1.0f + __expf(-x)); }
__device__ __forceinline__ float tanhf_fast(float x){
  float e = __expf(2.0f * x);
  return 1.0f - 2.0f / (e + 1.0f);
}
__device__ __forceinline__ f32x4 mfma_bf16(short8 a, short8 b, f32x4 c){
  return __builtin_amdgcn_mfma_f32_16x16x32_bf16(a, b, c, 0, 0, 0);
}

// ---- LLC-coherent (sc0 sc1) helpers; internal vmcnt(0) only (round-4 lesson).
__device__ __forceinline__ void load8_bypass(const unsigned short* p, short8* d){
  asm volatile(
    "global_load_dwordx4 %0, %8, off sc0 sc1\n\t"
    "global_load_dwordx4 %1, %8, off offset:64 sc0 sc1\n\t"
    "global_load_dwordx4 %2, %8, off offset:128 sc0 sc1\n\t"
    "global_load_dwordx4 %3, %8, off offset:192 sc0 sc1\n\t"
    "global_load_dwordx4 %4, %8, off offset:256 sc0 sc1\n\t"
    "global_load_dwordx4 %5, %8, off offset:320 sc0 sc1\n\t"
    "global_load_dwordx4 %6, %8, off offset:384 sc0 sc1\n\t"
    "global_load_dwordx4 %7, %8, off offset:448 sc0 sc1\n\t"
    "s_waitcnt vmcnt(0)"
    : "=&v"(d[0]), "=&v"(d[1]), "=&v"(d[2]), "=&v"(d[3]),
      "=&v"(d[4]), "=&v"(d[5]), "=&v"(d[6]), "=&v"(d[7])
    : "v"(p)
    : "memory");
}
__device__ __forceinline__ void store_short_bypass(unsigned short* p, unsigned v){
  asm volatile("global_store_short %0, %1, off sc0 sc1" :: "v"(p), "v"(v) : "memory");
}
__device__ __forceinline__ void store_dword_bypass(unsigned* p, unsigned v){
  asm volatile("global_store_dword %0, %1, off sc0 sc1" :: "v"(p), "v"(v) : "memory");
}
__device__ __forceinline__ uint4v load4_flags_bypass(const unsigned* p){
  uint4v f;
  asm volatile("global_load_dwordx4 %0, %1, off sc0 sc1\n\ts_waitcnt vmcnt(0)"
               : "=&v"(f) : "v"(p) : "memory");
  return f;
}

// ---------------------------------------------------------------------------
// fused pre-pass (single dispatch): convert In f32->bf16 (4 elems/thread) AND
// pack W_hh/W_ih into per-(cb,wave,gate,ks) MFMA-B-fragment order, bias sum,
// h0 seed. All parts elementwise & independent.
// grid 32768 x 256: i in [0, 8.4M) covers 2 x 4.2M pack elems; i*4 covers In.
// ---------------------------------------------------------------------------
__global__ __launch_bounds__(256) void prep_kernel(
    const float* __restrict__ In, const float* __restrict__ Whh,
    const float* __restrict__ Wih, const float* __restrict__ bih,
    const float* __restrict__ bhh, const float* __restrict__ h0,
    unsigned short* __restrict__ InB, unsigned short* __restrict__ WpackHH,
    unsigned short* __restrict__ WpackIH, float* __restrict__ biasSum,
    unsigned short* __restrict__ hA){
  int i = blockIdx.x * 256 + threadIdx.x;
  // convert In: 4 consecutive f32 per thread (exactly covers 33,554,432)
  {
    size_t ci = (size_t)i * 4;
    f32x4 v = *reinterpret_cast<const f32x4*>(&In[ci]);
    ushort4v u; u[0]=f2bf(v[0]); u[1]=f2bf(v[1]); u[2]=f2bf(v[2]); u[3]=f2bf(v[3]);
    *reinterpret_cast<ushort4v*>(&InB[ci]) = u;
  }
  if (i < G4) biasSum[i] = bih[i] + bhh[i];
  if (i < BATCH*HDIM) hA[i] = f2bf(h0[i]);
  int p = (i < G4*HDIM) ? i : i - G4*HDIM;
  int e = p & 7, l = (p >> 3) & 63, ks = (p >> 9) & 7;
  int gate = (p >> 12) & 3, w = (p >> 14) & 3, cb = p >> 16;
  int row = gate * HDIM + cb * 16 + (l & 15);
  int k = w * 256 + ks * 32 + (l >> 4) * 8 + e;
  if (i < G4*HDIM) WpackHH[p] = f2bf(Whh[row * HDIM + k]);
  else             WpackIH[p] = f2bf(Wih[row * IDIM + k]);
}

// ---------------------------------------------------------------------------
// FUSED recurrence (round-14 verbatim — best measured: 2333 us profiled):
// In(s+2) bf16 prefetch issued right after the h-load (hidden under
// MFMA/reduce; collected by the pre-flag vmcnt(0); poll sees a clean
// counter). Register double-buffer inrA/inrB via 2-step unrolled loop.
// Vectorized LDS partials (0 bank conflicts). r7 per-group flag barrier.
// ---------------------------------------------------------------------------
__global__ __launch_bounds__(256, 1) void recur_kernel(
    const float* __restrict__ h0, const float* __restrict__ c0,
    const float* __restrict__ ret, const unsigned short* __restrict__ WpackHH,
    const unsigned short* __restrict__ WpackIH, const unsigned short* __restrict__ InB,
    const float* __restrict__ biasSum, unsigned short* __restrict__ hA,
    unsigned short* __restrict__ hB, float* __restrict__ out,
    float* __restrict__ hc_out, unsigned* __restrict__ flags){
  __shared__ __align__(16) float partA[5120];   // [(m*16+n)*20 + w*4 + gate]
  __shared__ __align__(16) float partB[5120];

  const int bid = blockIdx.x;
  const int cb = bid & 63, g = bid >> 6;
  const int tid = threadIdx.x;
  const int w = tid >> 6, l = tid & 63;
  const int lm = l & 15, lq = l >> 4;

  // W fragments for this (cb, wave): hh + ih, 4 gates x 8 ks each
  short8 WfH[4][8], WfI[4][8];
  {
    const short8* wph = reinterpret_cast<const short8*>(WpackHH)
                      + (size_t)(cb * 4 + w) * 2048 + l;
    const short8* wpi = reinterpret_cast<const short8*>(WpackIH)
                      + (size_t)(cb * 4 + w) * 2048 + l;
    #pragma unroll
    for (int gate = 0; gate < 4; ++gate)
      #pragma unroll
      for (int ks = 0; ks < 8; ++ks){
        WfH[gate][ks] = wph[(gate * 8 + ks) * 64];
        WfI[gate][ks] = wpi[(gate * 8 + ks) * 64];
      }
  }

  const int bl = tid >> 4, j = tid & 15;   // batch-in-group, col-in-block
  const int bglob = g * 16 + bl, jglob = cb * 16 + j;
  float c_reg = c0[bglob * HDIM + jglob];
  float h_reg = h0[bglob * HDIM + jglob];
  float r_reg = ret[jglob];
  float bias_reg[4];
  #pragma unroll
  for (int gate = 0; gate < 4; ++gate)
    bias_reg[gate] = biasSum[gate * 1024 + jglob];

  // per-lane In source offset (same fragment geometry as h)
  const size_t in_off = (size_t)(g * 16 + lm) * 1024 + w * 256 + lq * 8;

  unsigned* gflags = flags + g * 1024;   // one 64B line per block: [cb*16 + w]

  // ---- prologue: compute xv(0) from In(0) ----
  float xv[4];
  {
    short8 inr0[8];
    const short8* ip = reinterpret_cast<const short8*>(InB + in_off);
    #pragma unroll
    for (int ks = 0; ks < 8; ++ks) inr0[ks] = ip[ks * 4];
    f32x4 accI[4];
    #pragma unroll
    for (int gate = 0; gate < 4; ++gate) accI[gate] = (f32x4){0.f,0.f,0.f,0.f};
    #pragma unroll
    for (int ks = 0; ks < 8; ++ks)
      #pragma unroll
      for (int gate = 0; gate < 4; ++gate)
        accI[gate] = mfma_bf16(inr0[ks], WfI[gate][ks], accI[gate]);
    #pragma unroll
    for (int r = 0; r < 4; ++r){
      f32x4 vB = (f32x4){accI[0][r], accI[1][r], accI[2][r], accI[3][r]};
      *reinterpret_cast<f32x4*>(&partB[((lq * 4 + r) * 16 + lm) * 20 + w * 4]) = vB;
    }
    __syncthreads();
    f32x4 s0 = (f32x4){bias_reg[0], bias_reg[1], bias_reg[2], bias_reg[3]};
    #pragma unroll
    for (int ww = 0; ww < 4; ++ww)
      s0 += *reinterpret_cast<const f32x4*>(&partB[tid * 20 + ww * 4]);
    xv[0] = s0[0]; xv[1] = s0[1]; xv[2] = s0[2]; xv[3] = s0[3];
    __syncthreads();   // protect partB before loop reuse
  }

  // preload In(1) fragment registers (consumed at s=0)
  short8 inrA[8], inrB[8];
  {
    const short8* ip = reinterpret_cast<const short8*>(InB + 65536 + in_off);
    #pragma unroll
    for (int ks = 0; ks < 8; ++ks) inrA[ks] = ip[ks * 4];
  }

  // ---- one recurrence step; inrUse holds In(s+1), inrPre gets In(s+2) ----
#define STEP(S, CUR, NXT, INR_USE, INR_PRE)                                     \
  {                                                                             \
    const int s = (S);                                                          \
    const unsigned short* hp = (CUR) + (size_t)(g * 16 + lm) * HDIM             \
                             + w * 256 + lq * 8;                                \
    short8 hr[8];                                                               \
    load8_bypass(hp, hr);                                                       \
    /* In(s+2) prefetch NOW: hidden under MFMA/reduce, drained by h'-drain */   \
    {                                                                           \
      const int sn = (s + 2 < S_LEN) ? s + 2 : S_LEN - 1;                       \
      const short8* ipn = reinterpret_cast<const short8*>(                      \
          InB + (size_t)sn * 65536 + in_off);                                   \
      _Pragma("unroll")                                                         \
      for (int ks = 0; ks < 8; ++ks) INR_PRE[ks] = ipn[ks * 4];                 \
    }                                                                           \
    f32x4 accH[4], accI[4];                                                     \
    _Pragma("unroll")                                                           \
    for (int gate = 0; gate < 4; ++gate){                                       \
      accH[gate] = (f32x4){0.f,0.f,0.f,0.f};                                    \
      accI[gate] = (f32x4){0.f,0.f,0.f,0.f};                                    \
    }                                                                           \
    _Pragma("unroll")                                                           \
    for (int ks = 0; ks < 8; ++ks){                                             \
      accH[0] = mfma_bf16(hr[ks], WfH[0][ks], accH[0]);                         \
      accH[1] = mfma_bf16(hr[ks], WfH[1][ks], accH[1]);                         \
      accH[2] = mfma_bf16(hr[ks], WfH[2][ks], accH[2]);                         \
      accH[3] = mfma_bf16(hr[ks], WfH[3][ks], accH[3]);                         \
      accI[0] = mfma_bf16(INR_USE[ks], WfI[0][ks], accI[0]);                    \
      accI[1] = mfma_bf16(INR_USE[ks], WfI[1][ks], accI[1]);                    \
      accI[2] = mfma_bf16(INR_USE[ks], WfI[2][ks], accI[2]);                    \
      accI[3] = mfma_bf16(INR_USE[ks], WfI[3][ks], accI[3]);                    \
    }                                                                           \
    _Pragma("unroll")                                                           \
    for (int r = 0; r < 4; ++r){                                                \
      int a = ((lq * 4 + r) * 16 + lm) * 20 + w * 4;                            \
      f32x4 vA = (f32x4){accH[0][r], accH[1][r], accH[2][r], accH[3][r]};       \
      f32x4 vB = (f32x4){accI[0][r], accI[1][r], accI[2][r], accI[3][r]};       \
      *reinterpret_cast<f32x4*>(&partA[a]) = vA;                                \
      *reinterpret_cast<f32x4*>(&partB[a]) = vB;                                \
    }                                                                           \
    __syncthreads();  /* sync#1 */                                              \
    f32x4 gs = (f32x4){xv[0], xv[1], xv[2], xv[3]};                             \
    _Pragma("unroll")                                                           \
    for (int ww = 0; ww < 4; ++ww)                                              \
      gs += *reinterpret_cast<const f32x4*>(&partA[tid * 20 + ww * 4]);         \
    float ig = sigf(gs[0]), fg = sigf(gs[1]);                                   \
    float gt = tanhf_fast(gs[2]), og = sigf(gs[3]);                             \
    float cy = fg * c_reg + ig * gt;                                            \
    float hy = og * tanhf_fast(cy);                                             \
    hy = r_reg * h_reg + (1.0f - r_reg) * hy;                                   \
    c_reg = cy; h_reg = hy;                                                     \
    store_short_bypass(&(NXT)[bglob * HDIM + jglob], (unsigned)f2bf(hy));       \
    asm volatile("s_waitcnt vmcnt(0)" ::: "memory");  /* h' + prefetch done */  \
    const unsigned tgt = (unsigned)(s + 1);                                     \
    if (l == 0)                                                                 \
      store_dword_bypass(&gflags[cb * 16 + w], tgt);                            \
    { /* reduce ih -> xv(s+1), off the inter-block critical path */             \
      f32x4 sB = (f32x4){bias_reg[0], bias_reg[1], bias_reg[2], bias_reg[3]};   \
      _Pragma("unroll")                                                         \
      for (int ww = 0; ww < 4; ++ww)                                            \
        sB += *reinterpret_cast<const f32x4*>(&partB[tid * 20 + ww * 4]);       \
      xv[0] = sB[0]; xv[1] = sB[1]; xv[2] = sB[2]; xv[3] = sB[3];               \
    }                                                                           \
    if (w == 0){  /* wave 0 polls with a CLEAN vmcnt */                         \
      const unsigned* fp = gflags + (l << 4);                                   \
      unsigned spins = 0;                                                       \
      for (;;){                                                                 \
        uint4v f = load4_flags_bypass(fp);                                      \
        if (f[0] >= tgt && f[1] >= tgt && f[2] >= tgt && f[3] >= tgt) break;    \
        __builtin_amdgcn_s_sleep(1);                                            \
        if (++spins > 50000000u) break;                                         \
      }                                                                         \
    }                                                                           \
    __syncthreads();  /* sync#2 */                                              \
    out[((size_t)s * BATCH + bglob) * HDIM + jglob] = h_reg;                    \
  }

  for (int s2 = 0; s2 < S_LEN; s2 += 2){
    STEP(s2,     hA, hB, inrA, inrB)
    STEP(s2 + 1, hB, hA, inrB, inrA)
  }
#undef STEP

  hc_out[bglob * HDIM + jglob] = h_reg;
  hc_out[BATCH * HDIM + bglob * HDIM + jglob] = c_reg;
}

// ---------------------------------------------------------------------------
extern "C" void kernel_launch(void* const* d_in, const int* in_sizes, int n_in,
                              void* d_out, int out_size, void* d_ws, size_t ws_size,
                              hipStream_t stream){
  const float* In  = (const float*)d_in[0];
  const float* h0  = (const float*)d_in[1];
  const float* c0  = (const float*)d_in[2];
  const float* Wih = (const float*)d_in[3];
  const float* Whh = (const float*)d_in[4];
  const float* bih = (const float*)d_in[5];
  const float* bhh = (const float*)d_in[6];
  const float* ret = (const float*)d_in[7];
  float* out = (float*)d_out;

  char* ws = (char*)d_ws;
  const size_t off_flags = 0;                          // 16 KB (4 groups x 4 KB)
  const size_t off_bias  = 16384;                      // 16 KB
  const size_t off_hA    = 32768;                      // 128 KB
  const size_t off_hB    = off_hA + 131072;
  const size_t off_wph   = off_hB + 131072;            // 8 MB (Whh pack)
  const size_t off_wpi   = off_wph + 8388608;          // 8 MB (Wih pack)
  const size_t off_inb   = off_wpi + 8388608;          // 64 MB (In bf16)
  const size_t need      = off_inb + 67108864;

  unsigned*       flags   = (unsigned*)(ws + off_flags);
  float*          biasSum = (float*)(ws + off_bias);
  unsigned short* hA      = (unsigned short*)(ws + off_hA);
  unsigned short* hB      = (unsigned short*)(ws + off_hB);
  unsigned short* WpackHH = (unsigned short*)(ws + off_wph);
  unsigned short* WpackIH = (unsigned short*)(ws + off_wpi);
  unsigned short* InB     = (unsigned short*)(ws + off_inb);

  if (ws_size < need) return;  // cannot run; fail validation loudly

  (void)hipMemsetAsync(ws + off_flags, 0, 16384, stream);
  prep_kernel<<<32768, 256, 0, stream>>>(In, Whh, Wih, bih, bhh, h0,
                                         InB, WpackHH, WpackIH, biasSum, hA);

  float* hc_out = out + (size_t)S_LEN * BATCH * HDIM;
  recur_kernel<<<NBLK, 256, 0, stream>>>(h0, c0, ret, WpackHH, WpackIH, InB,
                                         biasSum, hA, hB, out, hc_out, flags);
}